// Round 2
// baseline (2647.701 us; speedup 1.0000x reference)
//
#include <hip/hip_runtime.h>
#include <hip/hip_bf16.h>
#include <stdint.h>

// Problem constants (fixed by the reference)
#define N_NODES 100000
#define N_EDGES 400000
#define N_GRAPH 4096
#define DIMD    300
#define NLAYER  5
// padded GEMM dims
#define KP1    320   // padded D (K of GEMM1)
#define W1ROWS 640   // w1b B-rows (5 col-tiles of 128 for GEMM1)
#define HP     608   // padded H = t width = K of GEMM2 (19*32)
#define WID2   384   // padded out-width of GEMM2 (3 tiles of 128)
#define NSLAB  5
#define SLAB   20000 // N_NODES / NSLAB

typedef __attribute__((ext_vector_type(8))) short bf16x8_t;
typedef __attribute__((ext_vector_type(4))) float f32x4_t;

__device__ __forceinline__ void gload_lds16(const void* g, void* l) {
  auto gp = (__attribute__((address_space(1))) void*)(uintptr_t)g;
  auto lp = (__attribute__((address_space(3))) void*)(uint32_t)(uintptr_t)l;
  __builtin_amdgcn_global_load_lds(gp, lp, 16, 0, 0);
}

// ---------------- CSR build ----------------
__global__ void k_hist(const int* __restrict__ ei, int* __restrict__ cur) {
  const int e = blockIdx.x * blockDim.x + threadIdx.x;
  if (e < N_EDGES) atomicAdd(&cur[ei[N_EDGES + e]], 1);
}

__global__ void k_scan1(int* __restrict__ cur, int* __restrict__ off, int* __restrict__ bsum) {
  __shared__ int buf[1024];
  const int tid = threadIdx.x;
  const int i = blockIdx.x * 1024 + tid;
  int v = (i < N_NODES) ? cur[i] : 0;
  buf[tid] = v;
  __syncthreads();
  for (int s = 1; s < 1024; s <<= 1) {
    int t = (tid >= s) ? buf[tid - s] : 0;
    __syncthreads();
    buf[tid] += t;
    __syncthreads();
  }
  if (i < N_NODES) { off[i + 1] = buf[tid]; cur[i] = 0; }
  if (tid == 1023) bsum[blockIdx.x] = buf[1023];
}

__global__ void k_scan2(int* __restrict__ bsum, int nb) {
  if (threadIdx.x == 0 && blockIdx.x == 0) {
    int run = 0;
    for (int b = 0; b < nb; ++b) { int v = bsum[b]; bsum[b] = run; run += v; }
  }
}

__global__ void k_scan3(int* __restrict__ off, const int* __restrict__ bsum) {
  const int i = blockIdx.x * blockDim.x + threadIdx.x;
  if (i == 0) off[0] = 0;
  if (i < N_NODES) off[i + 1] += bsum[i >> 10];
}

__global__ void k_fill(const int* __restrict__ ei, const int* __restrict__ ea,
                       const int* __restrict__ off, int* __restrict__ cur,
                       int* __restrict__ csr) {
  const int e = blockIdx.x * blockDim.x + threadIdx.x;
  if (e < N_EDGES) {
    const int d = ei[N_EDGES + e];
    const int pos = atomicAdd(&cur[d], 1);
    const int c = ea[2 * e] * 3 + ea[2 * e + 1];   // attr values in [0,3)
    csr[off[d] + pos] = (ei[e] << 4) | c;          // src<<4 | comb-index
  }
}

// ---------------- small precompute ----------------
__global__ void k_comb(const float* __restrict__ e1, const float* __restrict__ e2,
                       float* __restrict__ comb) {
  const int idx = blockIdx.x * blockDim.x + threadIdx.x;
  if (idx >= NLAYER * 10 * DIMD) return;
  const int l = idx / (10 * DIMD);
  const int r = (idx / DIMD) % 10;
  const int d = idx % DIMD;
  int a, b;
  if (r < 9) { a = r / 3; b = r % 3; } else { a = 4; b = 0; }
  comb[idx] = e1[(l * 6 + a) * DIMD + d] + e2[(l * 3 + b) * DIMD + d];
}

// w1 (L,300,600) f32 -> w1b (L,[640 n][320 k]) bf16, zero-padded
__global__ void k_wc1(const float* __restrict__ w, __hip_bfloat16* __restrict__ wb) {
  const int idx = blockIdx.x * blockDim.x + threadIdx.x;
  if (idx >= NLAYER * W1ROWS * KP1) return;
  const int l = idx / (W1ROWS * KP1);
  const int n = (idx / KP1) % W1ROWS;
  const int k = idx % KP1;
  float v = 0.f;
  if (n < 600 && k < DIMD) v = w[((long)l * DIMD + k) * 600 + n];
  wb[idx] = __float2bfloat16(v);
}

// w2 (L,600,300) f32 -> w2b (L,[384 n][608 k]) bf16, zero-padded
__global__ void k_wc2(const float* __restrict__ w, __hip_bfloat16* __restrict__ wb) {
  const int idx = blockIdx.x * blockDim.x + threadIdx.x;
  if (idx >= NLAYER * WID2 * HP) return;
  const int l = idx / (WID2 * HP);
  const int n = (idx / HP) % WID2;
  const int k = idx % HP;
  float v = 0.f;
  if (n < DIMD && k < 600) v = w[((long)l * 600 + k) * DIMD + n];
  wb[idx] = __float2bfloat16(v);
}

__global__ void k_nemb(const int* __restrict__ x, const float* __restrict__ ae1,
                       const float* __restrict__ ae2, float* __restrict__ h) {
  const int node = blockIdx.x;
  const int d = threadIdx.x;
  if (d < DIMD)
    h[(long)node * DIMD + d] = ae1[x[2 * node] * DIMD + d] + ae2[x[2 * node + 1] * DIMD + d];
}

// ---------------- aggregation: one wave per node, writes bf16 GEMM1 operand ----------------
__global__ __launch_bounds__(256)
void k_agg(const float* __restrict__ h, __hip_bfloat16* __restrict__ aggb,
           const int* __restrict__ csr, const int* __restrict__ off,
           const float* __restrict__ comb) {
  const int wv = threadIdx.x >> 6;
  const int lane = threadIdx.x & 63;
  const int node = blockIdx.x * 4 + wv;
  if (node >= N_NODES) return;
  const int p0 = off[node], p1 = off[node + 1];
  const long hb = (long)node * DIMD;
  float acc[5];
#pragma unroll
  for (int j = 0; j < 5; ++j) {
    const int d = lane + j * 64;
    acc[j] = (d < DIMD) ? (h[hb + d] + comb[9 * DIMD + d]) : 0.f;  // h + self_emb
  }
  for (int p = p0; p < p1; ++p) {
    const int v = csr[p];
    const int s = v >> 4;
    const int c = v & 15;
    const long sb = (long)s * DIMD;
#pragma unroll
    for (int j = 0; j < 5; ++j) {
      const int d = lane + j * 64;
      if (d < DIMD) acc[j] += h[sb + d] + comb[c * DIMD + d];
    }
  }
  const long ab = (long)node * KP1;
#pragma unroll
  for (int j = 0; j < 5; ++j) {
    const int d = lane + j * 64;
    aggb[ab + d] = __float2bfloat16(d < DIMD ? acc[j] : 0.f);      // pad cols 300..319 = 0
  }
}

// ---------------- bf16 MFMA GEMM (m97-style 128x128 tile, B^T operand) ----------------
// epi 0: Cb[row*ldc+col] = bf16(col<storeCols ? relu(acc+bias[col]) : 0), stored when col<ldc
// epi 1: Cf[row*ldc+col] = BN(acc + bias[col]) (+relu), stored when col<storeCols
__global__ __launch_bounds__(256)
void k_gemm(const __hip_bfloat16* __restrict__ A, const __hip_bfloat16* __restrict__ Bt,
            int M, int K, int nColTiles, int epi, int storeCols, int ldc, int reluFlag,
            __hip_bfloat16* __restrict__ Cb, float* __restrict__ Cf,
            const float* __restrict__ bias, const float* __restrict__ bng,
            const float* __restrict__ bnb, const float* __restrict__ bnm,
            const float* __restrict__ bnv) {
  __shared__ __align__(16) __hip_bfloat16 As[128 * 32];
  __shared__ __align__(16) __hip_bfloat16 Bs[128 * 32];
  const int tid = threadIdx.x;
  const int lane = tid & 63;
  const int wv = tid >> 6;
  const int rowT = blockIdx.x / nColTiles;
  const int colT = blockIdx.x % nColTiles;
  const int row0 = rowT * 128;
  const int col0 = colT * 128;

  f32x4_t acc[4][4];
#pragma unroll
  for (int m = 0; m < 4; ++m)
#pragma unroll
    for (int n = 0; n < 4; ++n) acc[m][n] = (f32x4_t){0.f, 0.f, 0.f, 0.f};

  const int wrow = (wv >> 1) * 64;
  const int wcol = (wv & 1) * 64;
  const int fr = lane & 15;
  const int kb = (lane >> 4) * 8;
  const int subr = lane >> 2;
  const int subb = (lane & 3) * 16;
  const long lda_b = (long)K * 2;

  for (int k0 = 0; k0 < K; k0 += 32) {
    __syncthreads();
#pragma unroll
    for (int it = 0; it < 2; ++it) {
      const int c = wv + it * 4;
      int ar = row0 + c * 16 + subr;
      if (ar >= M) ar = M - 1;        // M-tail: clamp loads, stores are guarded
      gload_lds16((const char*)A + (long)ar * lda_b + (long)k0 * 2 + subb,
                  (char*)As + c * 1024);
      const int br = col0 + c * 16 + subr;  // Bt has nColTiles*128 rows (zero-padded)
      gload_lds16((const char*)Bt + (long)br * lda_b + (long)k0 * 2 + subb,
                  (char*)Bs + c * 1024);
    }
    __syncthreads();

    bf16x8_t af[4], bfr[4];
#pragma unroll
    for (int m = 0; m < 4; ++m)
      af[m] = *(const bf16x8_t*)&As[(wrow + m * 16 + fr) * 32 + kb];
#pragma unroll
    for (int n = 0; n < 4; ++n)
      bfr[n] = *(const bf16x8_t*)&Bs[(wcol + n * 16 + fr) * 32 + kb];
#pragma unroll
    for (int m = 0; m < 4; ++m)
#pragma unroll
      for (int n = 0; n < 4; ++n)
        acc[m][n] = __builtin_amdgcn_mfma_f32_16x16x32_bf16(af[m], bfr[n], acc[m][n], 0, 0, 0);
  }

  const int r4 = (lane >> 4) * 4;
#pragma unroll
  for (int m = 0; m < 4; ++m) {
#pragma unroll
    for (int n = 0; n < 4; ++n) {
      const int col = col0 + wcol + n * 16 + fr;
#pragma unroll
      for (int r = 0; r < 4; ++r) {
        const int row = row0 + wrow + m * 16 + r4 + r;
        if (row >= M) continue;
        if (epi == 0) {
          if (col < ldc) {
            float v = 0.f;
            if (col < storeCols) v = fmaxf(acc[m][n][r] + bias[col], 0.f);
            Cb[(long)row * ldc + col] = __float2bfloat16(v);  // pad cols zeroed for GEMM2 K-pad
          }
        } else {
          if (col < storeCols) {
            float v = acc[m][n][r] + bias[col];
            v = (v - bnm[col]) * rsqrtf(bnv[col] + 1e-5f) * bng[col] + bnb[col];
            if (reluFlag) v = fmaxf(v, 0.f);
            Cf[(long)row * ldc + col] = v;
          }
        }
      }
    }
  }
}

// ---------------- pooling (batch is sorted -> binary search) + head ----------------
__device__ __forceinline__ int lbound(const int* a, int n, int key) {
  int lo = 0, hi = n;
  while (lo < hi) { int mid = (lo + hi) >> 1; if (a[mid] < key) lo = mid + 1; else hi = mid; }
  return lo;
}

__global__ void k_pool(const float* __restrict__ h, const int* __restrict__ batch,
                       float* __restrict__ pooled) {
  __shared__ int se[2];
  const int g = blockIdx.x;
  if (threadIdx.x < 2) se[threadIdx.x] = lbound(batch, N_NODES, g + threadIdx.x);
  __syncthreads();
  const int d = threadIdx.x;
  if (d < DIMD) {
    float a = 0.f;
    for (int i = se[0]; i < se[1]; ++i) a += h[(long)i * DIMD + d];
    pooled[(long)g * DIMD + d] = a;
  }
}

__global__ __launch_bounds__(256)
void k_head(const float* __restrict__ pooled, const float* __restrict__ hw1,
            const float* __restrict__ hb1, const float* __restrict__ hw2,
            const float* __restrict__ hb2, float* __restrict__ out) {
  __shared__ float sp[DIMD];
  __shared__ float r0[256], r1[256];
  const int g = blockIdx.x, tid = threadIdx.x;
  for (int d = tid; d < DIMD; d += 256) sp[d] = pooled[(long)g * DIMD + d];
  __syncthreads();
  float p0 = 0.f, p1 = 0.f;
  for (int j = tid; j < 512; j += 256) {
    float z = hb1[j];
    for (int d = 0; d < DIMD; ++d) z = fmaf(sp[d], hw1[d * 512 + j], z);
    z = fmaxf(z, 0.f);
    p0 = fmaf(z, hw2[2 * j], p0);
    p1 = fmaf(z, hw2[2 * j + 1], p1);
  }
  r0[tid] = p0; r1[tid] = p1;
  __syncthreads();
  for (int s = 128; s > 0; s >>= 1) {
    if (tid < s) { r0[tid] += r0[tid + s]; r1[tid] += r1[tid + s]; }
    __syncthreads();
  }
  if (tid == 0) { out[2 * g] = r0[0] + hb2[0]; out[2 * g + 1] = r1[0] + hb2[1]; }
}

// sentinel: signal "workspace too small" through the only visible channel
__global__ void k_sentinel(float* out) { out[threadIdx.x] = 1.0e6f; }

// ---------------- launch ----------------
extern "C" void kernel_launch(void* const* d_in, const int* in_sizes, int n_in,
                              void* d_out, int out_size, void* d_ws, size_t ws_size,
                              hipStream_t stream) {
  const int*   x     = (const int*)d_in[0];
  const int*   ei    = (const int*)d_in[1];
  const int*   ea    = (const int*)d_in[2];
  const int*   batch = (const int*)d_in[3];
  const float* ae1   = (const float*)d_in[4];
  const float* ae2   = (const float*)d_in[5];
  const float* ee1   = (const float*)d_in[6];
  const float* ee2   = (const float*)d_in[7];
  const float* w1    = (const float*)d_in[8];
  const float* b1    = (const float*)d_in[9];
  const float* w2    = (const float*)d_in[10];
  const float* b2    = (const float*)d_in[11];
  const float* bng   = (const float*)d_in[12];
  const float* bnbp  = (const float*)d_in[13];
  const float* bnm   = (const float*)d_in[14];
  const float* bnv   = (const float*)d_in[15];
  const float* hw1   = (const float*)d_in[16];
  const float* hb1   = (const float*)d_in[17];
  const float* hw2   = (const float*)d_in[18];
  const float* hb2   = (const float*)d_in[19];
  float* out = (float*)d_out;

  char* ws = (char*)d_ws;
  size_t o = 0;
  auto alloc = [&](size_t bytes) { size_t p = o; o += (bytes + 255) & ~(size_t)255; return p; };
  float*          h      = (float*)         (ws + alloc((size_t)N_NODES * DIMD * 4));   // 120 MB
  __hip_bfloat16* aggb   = (__hip_bfloat16*)(ws + alloc((size_t)N_NODES * KP1 * 2));    //  64 MB
  __hip_bfloat16* t      = (__hip_bfloat16*)(ws + alloc((size_t)SLAB * HP * 2));        //  24.3 MB
  __hip_bfloat16* w1b    = (__hip_bfloat16*)(ws + alloc((size_t)NLAYER * W1ROWS * KP1 * 2));
  __hip_bfloat16* w2b    = (__hip_bfloat16*)(ws + alloc((size_t)NLAYER * WID2 * HP * 2));
  float*          comb   = (float*)         (ws + alloc((size_t)NLAYER * 10 * DIMD * 4));
  int*            offp   = (int*)           (ws + alloc((size_t)(N_NODES + 1) * 4));
  int*            cur    = (int*)           (ws + alloc((size_t)N_NODES * 4));
  int*            csr    = (int*)           (ws + alloc((size_t)N_EDGES * 4));
  float*          pooled = (float*)         (ws + alloc((size_t)N_GRAPH * DIMD * 4));
  int*            bsum   = (int*)           (ws + alloc(128 * 4));
  if (o > ws_size) {                        // ~220 MB total
    k_sentinel<<<1, 8, 0, stream>>>(out);   // absmax ~1e6 => diagnose ws_size too small
    return;
  }

  hipMemsetAsync(cur, 0, (size_t)N_NODES * 4, stream);

  // CSR by dst (deterministic structure; intra-node order via atomics, fp-order noise only)
  k_hist<<<(N_EDGES + 255) / 256, 256, 0, stream>>>(ei, cur);
  const int nsb = (N_NODES + 1023) / 1024;
  k_scan1<<<nsb, 1024, 0, stream>>>(cur, offp, bsum);
  k_scan2<<<1, 64, 0, stream>>>(bsum, nsb);
  k_scan3<<<(N_NODES + 255) / 256, 256, 0, stream>>>(offp, bsum);
  k_fill<<<(N_EDGES + 255) / 256, 256, 0, stream>>>(ei, ea, offp, cur, csr);

  k_wc1<<<(NLAYER * W1ROWS * KP1 + 255) / 256, 256, 0, stream>>>(w1, w1b);
  k_wc2<<<(NLAYER * WID2 * HP + 255) / 256, 256, 0, stream>>>(w2, w2b);
  k_comb<<<(NLAYER * 10 * DIMD + 255) / 256, 256, 0, stream>>>(ee1, ee2, comb);
  k_nemb<<<N_NODES, 320, 0, stream>>>(x, ae1, ae2, h);

  const int rT = (SLAB + 127) / 128;  // 157
  for (int l = 0; l < NLAYER; ++l) {
    k_agg<<<(N_NODES + 3) / 4, 256, 0, stream>>>(h, aggb, csr, offp, comb + l * 10 * DIMD);
    for (int s = 0; s < NSLAB; ++s) {
      // t = relu(aggb_slab @ w1 + b1)  [bf16, 608 cols, 600..607 zeroed]
      k_gemm<<<rT * 5, 256, 0, stream>>>(aggb + (size_t)s * SLAB * KP1,
          w1b + (size_t)l * W1ROWS * KP1,
          SLAB, KP1, 5, 0, 600, HP, 0,
          t, nullptr, b1 + l * 600, nullptr, nullptr, nullptr, nullptr);
      // h_slab = BN(t @ w2 + b2) (+relu if l<4)  [f32, 300 cols]
      k_gemm<<<rT * 3, 256, 0, stream>>>(t, w2b + (size_t)l * WID2 * HP,
          SLAB, HP, 3, 1, DIMD, DIMD, (l < NLAYER - 1) ? 1 : 0,
          nullptr, h + (size_t)s * SLAB * DIMD, b2 + l * DIMD,
          bng + l * DIMD, bnbp + l * DIMD, bnm + l * DIMD, bnv + l * DIMD);
    }
  }

  k_pool<<<N_GRAPH, 320, 0, stream>>>(h, batch, pooled);
  k_head<<<N_GRAPH, 256, 0, stream>>>(pooled, hw1, hb1, hw2, hb2, out);
}

// Round 3
// 1982.177 us; speedup vs baseline: 1.3358x; 1.3358x over previous
//
#include <hip/hip_runtime.h>
#include <hip/hip_bf16.h>
#include <stdint.h>

// Problem constants (fixed by the reference)
#define N_NODES 100000
#define N_EDGES 400000
#define N_GRAPH 4096
#define DIMD    300
#define NLAYER  5
// padded dims
#define HPAD   304   // h row stride (bf16), 38 x 8
#define KP1    320   // aggb row stride = K of GEMM1 (5 x 64)
#define W1ROWS 640   // w1b rows (5 col-tiles of 128 for GEMM1) = t row stride = K of GEMM2 (10 x 64)
#define WID2   384   // w2b rows (3 col-tiles of 128 for GEMM2)
#define BK     64    // GEMM K-step

typedef __attribute__((ext_vector_type(8))) short bf16x8_t;
typedef __attribute__((ext_vector_type(4))) float f32x4_t;

__device__ __forceinline__ void gload_lds16(const void* g, void* l) {
  auto gp = (__attribute__((address_space(1))) void*)(uintptr_t)g;
  auto lp = (__attribute__((address_space(3))) void*)(uint32_t)(uintptr_t)l;
  __builtin_amdgcn_global_load_lds(gp, lp, 16, 0, 0);
}
__device__ __forceinline__ short f2bs(float f) {
  __hip_bfloat16 b = __float2bfloat16(f); return *(short*)&b;
}
__device__ __forceinline__ float bs2f(short s) {
  __hip_bfloat16 b; *(short*)&b = s; return __bfloat162float(b);
}

// ---------------- CSR build ----------------
__global__ void k_hist(const int* __restrict__ ei, int* __restrict__ cur) {
  const int e = blockIdx.x * blockDim.x + threadIdx.x;
  if (e < N_EDGES) atomicAdd(&cur[ei[N_EDGES + e]], 1);
}

__global__ void k_scan1(int* __restrict__ cur, int* __restrict__ off, int* __restrict__ bsum) {
  __shared__ int buf[1024];
  const int tid = threadIdx.x;
  const int i = blockIdx.x * 1024 + tid;
  int v = (i < N_NODES) ? cur[i] : 0;
  buf[tid] = v;
  __syncthreads();
  for (int s = 1; s < 1024; s <<= 1) {
    int t = (tid >= s) ? buf[tid - s] : 0;
    __syncthreads();
    buf[tid] += t;
    __syncthreads();
  }
  if (i < N_NODES) { off[i + 1] = buf[tid]; cur[i] = 0; }
  if (tid == 1023) bsum[blockIdx.x] = buf[1023];
}

__global__ void k_scan2(int* __restrict__ bsum, int nb) {
  if (threadIdx.x == 0 && blockIdx.x == 0) {
    int run = 0;
    for (int b = 0; b < nb; ++b) { int v = bsum[b]; bsum[b] = run; run += v; }
  }
}

__global__ void k_scan3(int* __restrict__ off, const int* __restrict__ bsum) {
  const int i = blockIdx.x * blockDim.x + threadIdx.x;
  if (i == 0) off[0] = 0;
  if (i < N_NODES) off[i + 1] += bsum[i >> 10];
}

__global__ void k_fill(const int* __restrict__ ei, const int* __restrict__ ea,
                       const int* __restrict__ off, int* __restrict__ cur,
                       int* __restrict__ csr) {
  const int e = blockIdx.x * blockDim.x + threadIdx.x;
  if (e < N_EDGES) {
    const int d = ei[N_EDGES + e];
    const int pos = atomicAdd(&cur[d], 1);
    const int c = ea[2 * e] * 3 + ea[2 * e + 1];   // attr values in [0,3)
    csr[off[d] + pos] = (ei[e] << 4) | c;          // src<<4 | comb-index
  }
}

// ---------------- small precompute ----------------
// comb[l][r][0..HPAD): r<9 -> ee1[l][r/3]+ee2[l][r%3]; r==9 -> self-loop; pad cols 0
__global__ void k_comb(const float* __restrict__ e1, const float* __restrict__ e2,
                       float* __restrict__ comb) {
  const int idx = blockIdx.x * blockDim.x + threadIdx.x;
  if (idx >= NLAYER * 10 * HPAD) return;
  const int l = idx / (10 * HPAD);
  const int r = (idx / HPAD) % 10;
  const int d = idx % HPAD;
  float v = 0.f;
  if (d < DIMD) {
    int a, b;
    if (r < 9) { a = r / 3; b = r % 3; } else { a = 4; b = 0; }
    v = e1[(l * 6 + a) * DIMD + d] + e2[(l * 3 + b) * DIMD + d];
  }
  comb[idx] = v;
}

// w1 (L,300,600) f32 -> w1b (L,[640 n][320 k]) bf16, zero-padded
__global__ void k_wc1(const float* __restrict__ w, __hip_bfloat16* __restrict__ wb) {
  const int idx = blockIdx.x * blockDim.x + threadIdx.x;
  if (idx >= NLAYER * W1ROWS * KP1) return;
  const int l = idx / (W1ROWS * KP1);
  const int n = (idx / KP1) % W1ROWS;
  const int k = idx % KP1;
  float v = 0.f;
  if (n < 600 && k < DIMD) v = w[((long)l * DIMD + k) * 600 + n];
  wb[idx] = __float2bfloat16(v);
}

// w2 (L,600,300) f32 -> w2b (L,[384 n][640 k]) bf16, zero-padded
__global__ void k_wc2(const float* __restrict__ w, __hip_bfloat16* __restrict__ wb) {
  const int idx = blockIdx.x * blockDim.x + threadIdx.x;
  if (idx >= NLAYER * WID2 * W1ROWS) return;
  const int l = idx / (WID2 * W1ROWS);
  const int n = (idx / W1ROWS) % WID2;
  const int k = idx % W1ROWS;
  float v = 0.f;
  if (n < DIMD && k < 600) v = w[((long)l * 600 + k) * DIMD + n];
  wb[idx] = __float2bfloat16(v);
}

// node input embedding -> bf16 h (one 16B chunk per thread)
__global__ void k_nemb(const int* __restrict__ x, const float* __restrict__ ae1,
                       const float* __restrict__ ae2, __hip_bfloat16* __restrict__ h) {
  const int gid = blockIdx.x * blockDim.x + threadIdx.x;
  if (gid >= N_NODES * 40) return;
  const int node = gid / 40;
  const int l = gid % 40;
  bf16x8_t ov;
#pragma unroll
  for (int j = 0; j < 8; ++j) ov[j] = 0;
  if (l < 38) {
    const int i0 = x[2 * node], i1 = x[2 * node + 1];
    const float* r1 = ae1 + (long)i0 * DIMD + l * 8;
    const float* r2 = ae2 + (long)i1 * DIMD + l * 8;
#pragma unroll
    for (int j = 0; j < 8; ++j) {
      const int d = l * 8 + j;
      if (d < DIMD) ov[j] = f2bs(r1[j] + r2[j]);
    }
  }
  *(bf16x8_t*)(h + (long)node * HPAD + l * 8) = ov;
}

// ---------------- aggregation: one wave/node, 16B-lane gathers over bf16 h ----------------
__global__ __launch_bounds__(256)
void k_agg(const __hip_bfloat16* __restrict__ h, __hip_bfloat16* __restrict__ aggb,
           const int* __restrict__ csr, const int* __restrict__ off,
           const float* __restrict__ comb) {
  const int wv = threadIdx.x >> 6;
  const int lane = threadIdx.x & 63;
  const int node = blockIdx.x * 4 + wv;
  if (node >= N_NODES) return;
  if (lane >= 40) return;                 // 40 lanes cover KP1=320 output cols
  const bool act = lane < 38;             // 38 lanes cover HPAD=304 input cols
  float acc[8];
  if (act) {
    const bf16x8_t hv = *(const bf16x8_t*)(h + (long)node * HPAD + lane * 8);
    const float* c9 = comb + 9 * HPAD + lane * 8;
#pragma unroll
    for (int j = 0; j < 8; ++j) acc[j] = bs2f(hv[j]) + c9[j];  // h + self_emb (pads are 0+0)
  } else {
#pragma unroll
    for (int j = 0; j < 8; ++j) acc[j] = 0.f;
  }
  const int p0 = off[node], p1 = off[node + 1];
  for (int p = p0; p < p1; ++p) {
    const int v = csr[p];
    const int s = v >> 4;
    const int c = v & 15;
    if (act) {
      const bf16x8_t hv = *(const bf16x8_t*)(h + (long)s * HPAD + lane * 8);
      const float* cc = comb + c * HPAD + lane * 8;
#pragma unroll
      for (int j = 0; j < 8; ++j) acc[j] += bs2f(hv[j]) + cc[j];
    }
  }
  bf16x8_t ov;
#pragma unroll
  for (int j = 0; j < 8; ++j) ov[j] = act ? f2bs(acc[j]) : (short)0;
  *(bf16x8_t*)(aggb + (long)node * KP1 + lane * 8) = ov;   // cols 304..319 = 0
}

// ---------------- bf16 MFMA GEMM: 128x128 tile, BK=64, both-sides XOR swizzle ----------------
// epi 0: t[row*ldc+col] = bf16(col<storeCols ? relu(acc+bias[col]) : 0)   stored for col<ldc
// epi 1: h[row*ldc+col] = bf16(col<storeCols ? BN(acc+bias[col])(+relu) : 0) stored for col<ldc
__global__ __launch_bounds__(256)
void k_gemm(const __hip_bfloat16* __restrict__ A, const __hip_bfloat16* __restrict__ Bt,
            int M, int K, int nColTiles, int epi, int storeCols, int ldc, int reluFlag,
            __hip_bfloat16* __restrict__ C,
            const float* __restrict__ bias, const float* __restrict__ bng,
            const float* __restrict__ bnb, const float* __restrict__ bnm,
            const float* __restrict__ bnv) {
  __shared__ __align__(16) char As[128 * 128];   // 128 rows x 64 bf16 (128B)
  __shared__ __align__(16) char Bs[128 * 128];
  const int tid = threadIdx.x;
  const int lane = tid & 63;
  const int wv = tid >> 6;
  const int rowT = blockIdx.x / nColTiles;
  const int colT = blockIdx.x % nColTiles;
  const int row0 = rowT * 128;
  const int col0 = colT * 128;

  f32x4_t acc[4][4];
#pragma unroll
  for (int m = 0; m < 4; ++m)
#pragma unroll
    for (int n = 0; n < 4; ++n) acc[m][n] = (f32x4_t){0.f, 0.f, 0.f, 0.f};

  const int wrow = (wv >> 1) * 64;
  const int wcol = (wv & 1) * 64;
  const int fr = lane & 15;
  const int kgrp = (lane >> 4) * 16;       // byte offset of the 8-elem K-group in a 64B half
  const long lda_b = (long)K * 2;

  for (int k0 = 0; k0 < K; k0 += BK) {
    __syncthreads();
#pragma unroll
    for (int it = 0; it < 4; ++it) {
      const int idx = it * 256 + tid;      // 1024 chunks of 16B per operand
      const int r = idx >> 3;              // 0..127
      const int b = (idx & 7) * 16;        // 0..112
      const int bs = b ^ ((r & 7) << 4);   // pre-swizzled SOURCE (rule #21)
      int ar = row0 + r;
      if (ar >= M) ar = M - 1;             // M-tail: clamp loads, stores guarded
      gload_lds16((const char*)A + (long)ar * lda_b + (long)k0 * 2 + bs, As + idx * 16);
      const int br = col0 + r;             // Bt rows = nColTiles*128 (zero-padded)
      gload_lds16((const char*)Bt + (long)br * lda_b + (long)k0 * 2 + bs, Bs + idx * 16);
    }
    __syncthreads();
#pragma unroll
    for (int kk = 0; kk < 2; ++kk) {
      bf16x8_t af[4], bfr[4];
#pragma unroll
      for (int m = 0; m < 4; ++m) {
        const int r = wrow + m * 16 + fr;
        const int b = (kk * 64 + kgrp) ^ ((r & 7) << 4);   // swizzled READ
        af[m] = *(const bf16x8_t*)(As + r * 128 + b);
      }
#pragma unroll
      for (int n = 0; n < 4; ++n) {
        const int r = wcol + n * 16 + fr;
        const int b = (kk * 64 + kgrp) ^ ((r & 7) << 4);
        bfr[n] = *(const bf16x8_t*)(Bs + r * 128 + b);
      }
#pragma unroll
      for (int m = 0; m < 4; ++m)
#pragma unroll
        for (int n = 0; n < 4; ++n)
          acc[m][n] = __builtin_amdgcn_mfma_f32_16x16x32_bf16(af[m], bfr[n], acc[m][n], 0, 0, 0);
    }
  }

  const int r4 = (lane >> 4) * 4;
#pragma unroll
  for (int m = 0; m < 4; ++m) {
#pragma unroll
    for (int n = 0; n < 4; ++n) {
      const int col = col0 + wcol + n * 16 + fr;
      if (col >= ldc) continue;
#pragma unroll
      for (int r = 0; r < 4; ++r) {
        const int row = row0 + wrow + m * 16 + r4 + r;
        if (row >= M) continue;
        float v = 0.f;
        if (col < storeCols) {
          v = acc[m][n][r] + bias[col];
          if (epi == 0) {
            v = fmaxf(v, 0.f);
          } else {
            v = (v - bnm[col]) * rsqrtf(bnv[col] + 1e-5f) * bng[col] + bnb[col];
            if (reluFlag) v = fmaxf(v, 0.f);
          }
        }
        C[(long)row * ldc + col] = __float2bfloat16(v);   // pad cols written as 0
      }
    }
  }
}

// ---------------- pooling (batch sorted -> binary search) + head ----------------
__device__ __forceinline__ int lbound(const int* a, int n, int key) {
  int lo = 0, hi = n;
  while (lo < hi) { int mid = (lo + hi) >> 1; if (a[mid] < key) lo = mid + 1; else hi = mid; }
  return lo;
}

__global__ void k_pool(const __hip_bfloat16* __restrict__ h, const int* __restrict__ batch,
                       float* __restrict__ pooled) {
  __shared__ int se[2];
  const int g = blockIdx.x;
  if (threadIdx.x < 2) se[threadIdx.x] = lbound(batch, N_NODES, g + threadIdx.x);
  __syncthreads();
  const int d = threadIdx.x;
  if (d < DIMD) {
    float a = 0.f;
    for (int i = se[0]; i < se[1]; ++i) a += __bfloat162float(h[(long)i * HPAD + d]);
    pooled[(long)g * DIMD + d] = a;
  }
}

__global__ __launch_bounds__(256)
void k_head(const float* __restrict__ pooled, const float* __restrict__ hw1,
            const float* __restrict__ hb1, const float* __restrict__ hw2,
            const float* __restrict__ hb2, float* __restrict__ out) {
  __shared__ float sp[DIMD];
  __shared__ float r0[256], r1[256];
  const int g = blockIdx.x, tid = threadIdx.x;
  for (int d = tid; d < DIMD; d += 256) sp[d] = pooled[(long)g * DIMD + d];
  __syncthreads();
  float p0 = 0.f, p1 = 0.f;
  for (int j = tid; j < 512; j += 256) {
    float z = hb1[j];
    for (int d = 0; d < DIMD; ++d) z = fmaf(sp[d], hw1[d * 512 + j], z);
    z = fmaxf(z, 0.f);
    p0 = fmaf(z, hw2[2 * j], p0);
    p1 = fmaf(z, hw2[2 * j + 1], p1);
  }
  r0[tid] = p0; r1[tid] = p1;
  __syncthreads();
  for (int s = 128; s > 0; s >>= 1) {
    if (tid < s) { r0[tid] += r0[tid + s]; r1[tid] += r1[tid + s]; }
    __syncthreads();
  }
  if (tid == 0) { out[2 * g] = r0[0] + hb2[0]; out[2 * g + 1] = r1[0] + hb2[1]; }
}

// sentinel: signal "workspace too small" through the only visible channel
__global__ void k_sentinel(float* out) { out[threadIdx.x] = 1.0e6f; }

// ---------------- launch ----------------
extern "C" void kernel_launch(void* const* d_in, const int* in_sizes, int n_in,
                              void* d_out, int out_size, void* d_ws, size_t ws_size,
                              hipStream_t stream) {
  const int*   x     = (const int*)d_in[0];
  const int*   ei    = (const int*)d_in[1];
  const int*   ea    = (const int*)d_in[2];
  const int*   batch = (const int*)d_in[3];
  const float* ae1   = (const float*)d_in[4];
  const float* ae2   = (const float*)d_in[5];
  const float* ee1   = (const float*)d_in[6];
  const float* ee2   = (const float*)d_in[7];
  const float* w1    = (const float*)d_in[8];
  const float* b1    = (const float*)d_in[9];
  const float* w2    = (const float*)d_in[10];
  const float* b2    = (const float*)d_in[11];
  const float* bng   = (const float*)d_in[12];
  const float* bnbp  = (const float*)d_in[13];
  const float* bnm   = (const float*)d_in[14];
  const float* bnv   = (const float*)d_in[15];
  const float* hw1   = (const float*)d_in[16];
  const float* hb1   = (const float*)d_in[17];
  const float* hw2   = (const float*)d_in[18];
  const float* hb2   = (const float*)d_in[19];
  float* out = (float*)d_out;

  char* ws = (char*)d_ws;
  size_t o = 0;
  auto alloc = [&](size_t bytes) { size_t p = o; o += (bytes + 255) & ~(size_t)255; return p; };
  __hip_bfloat16* h      = (__hip_bfloat16*)(ws + alloc((size_t)N_NODES * HPAD * 2));   // 60.8 MB
  __hip_bfloat16* aggb   = (__hip_bfloat16*)(ws + alloc((size_t)N_NODES * KP1 * 2));    // 64 MB
  __hip_bfloat16* w1b    = (__hip_bfloat16*)(ws + alloc((size_t)NLAYER * W1ROWS * KP1 * 2));
  __hip_bfloat16* w2b    = (__hip_bfloat16*)(ws + alloc((size_t)NLAYER * WID2 * W1ROWS * 2));
  float*          comb   = (float*)         (ws + alloc((size_t)NLAYER * 10 * HPAD * 4));
  int*            offp   = (int*)           (ws + alloc((size_t)(N_NODES + 1) * 4));
  int*            cur    = (int*)           (ws + alloc((size_t)N_NODES * 4));
  int*            csr    = (int*)           (ws + alloc((size_t)N_EDGES * 4));
  float*          pooled = (float*)         (ws + alloc((size_t)N_GRAPH * DIMD * 4));
  int*            bsum   = (int*)           (ws + alloc(128 * 4));

  // t gets the remaining space: pick the smallest slab count that fits
  const int cand[5] = {1, 2, 4, 5, 10};
  int nslab = -1, slabRows = 0;
  __hip_bfloat16* t = (__hip_bfloat16*)(ws + o);
  for (int i = 0; i < 5; ++i) {
    const int sr = (N_NODES + cand[i] - 1) / cand[i];
    if (o + (size_t)sr * W1ROWS * 2 <= ws_size) { nslab = cand[i]; slabRows = sr; break; }
  }
  if (nslab < 0) {
    k_sentinel<<<1, 8, 0, stream>>>(out);   // absmax ~1e6 => ws_size too small
    return;
  }

  hipMemsetAsync(cur, 0, (size_t)N_NODES * 4, stream);

  // CSR by dst (deterministic structure; intra-node order via atomics, fp-order noise only)
  k_hist<<<(N_EDGES + 255) / 256, 256, 0, stream>>>(ei, cur);
  const int nsb = (N_NODES + 1023) / 1024;
  k_scan1<<<nsb, 1024, 0, stream>>>(cur, offp, bsum);
  k_scan2<<<1, 64, 0, stream>>>(bsum, nsb);
  k_scan3<<<(N_NODES + 255) / 256, 256, 0, stream>>>(offp, bsum);
  k_fill<<<(N_EDGES + 255) / 256, 256, 0, stream>>>(ei, ea, offp, cur, csr);

  k_wc1<<<(NLAYER * W1ROWS * KP1 + 255) / 256, 256, 0, stream>>>(w1, w1b);
  k_wc2<<<(NLAYER * WID2 * W1ROWS + 255) / 256, 256, 0, stream>>>(w2, w2b);
  k_comb<<<(NLAYER * 10 * HPAD + 255) / 256, 256, 0, stream>>>(ee1, ee2, comb);
  k_nemb<<<(N_NODES * 40 + 255) / 256, 256, 0, stream>>>(x, ae1, ae2, h);

  for (int l = 0; l < NLAYER; ++l) {
    k_agg<<<(N_NODES + 3) / 4, 256, 0, stream>>>(h, aggb, csr, offp, comb + l * 10 * HPAD);
    for (int s = 0; s < nslab; ++s) {
      const int rows = (s == nslab - 1) ? (N_NODES - s * slabRows) : slabRows;
      const int rT = (rows + 127) / 128;
      // t = relu(aggb_slab @ w1 + b1)   [bf16, 640 cols, 600.. zeroed]
      k_gemm<<<rT * 5, 256, 0, stream>>>(aggb + (size_t)s * slabRows * KP1,
          w1b + (size_t)l * W1ROWS * KP1,
          rows, KP1, 5, 0, 600, W1ROWS, 0,
          t, b1 + l * 600, nullptr, nullptr, nullptr, nullptr);
      // h_slab = BN(t @ w2 + b2) (+relu if l<4)  [bf16, 304 cols, 300.. zeroed]
      k_gemm<<<rT * 3, 256, 0, stream>>>(t, w2b + (size_t)l * WID2 * W1ROWS,
          rows, W1ROWS, 3, 1, DIMD, HPAD, (l < NLAYER - 1) ? 1 : 0,
          h + (size_t)s * slabRows * HPAD, b2 + l * DIMD,
          bng + l * DIMD, bnbp + l * DIMD, bnm + l * DIMD, bnv + l * DIMD);
    }
  }

  k_pool<<<N_GRAPH, 320, 0, stream>>>(h, batch, pooled);
  k_head<<<N_GRAPH, 256, 0, stream>>>(pooled, hw1, hb1, hw2, hb2, out);
}